// Round 14
// baseline (403.357 us; speedup 1.0000x reference)
//
#include <hip/hip_runtime.h>
#include <string.h>

// TopographicIntentMap R14: 2 blocks/CU. R13 diagnosis: grid B/64 = 256 blocks
// = 1 block/CU -> every tick all 16 waves convoy on one barrier; wall/tick
// (29K cyc) = 2x max(DS 14.5K, VALU ~10K) because nothing overlaps across it.
// Fix: NB=32 batches, 512 threads, grid=512 = 2 independent blocks/CU whose
// barriers interleave. Wave = 2 row-groups x 32 batches (h=lane>>5, bb=lane&31),
// rows processed as nnz-sorted PAIRS (equal padded length kp per half, ~3% pad),
// snake-dealt to waves for balance. Stream layout chunk-interleaves the two
// halves so each lane runs R7's PROVEN flat mov-free depth-2 loop verbatim
// (prime q[0],q[1],q[4],q[5]; loop q[8],q[9]/q[12],q[13], q+=8; leftover q+=4)
// with a per-lane h*32 byte offset. Gathers stay ds_read_b32 (two 128B
// segments = free 2-way). acc f32 dbuf = 36.9KB -> 2 blocks/CU fit.
// Hazards avoided: one tick body (R9), one flat stream (R8), no packing (R10),
// no cross-unit per-entry (R11), per-lane stream loads (R13's FETCH blowup was
// sub-group-uniform loads; here every lane has a distinct or 32-shared addr and
// the whole stream is ~21KB shared by ALL blocks -> L2-resident).
// Numerics: exact-f64 pipeline of R3-R13 (absmax 0 all rounds); per-row rec
// k-ascending; pads +0.0; LIF verbatim.

#define NN 144
#define NE 115
#define NB 32            // batches per block
#define THREADS 512      // 8 waves x 9 pair-slots
#define SLOTS 9

#define STREAM_BASE 4096 // byte offset of pair-stream region in ws
#define META_STRIDE 32   // ints per wave in meta

__device__ __forceinline__ float u2f(unsigned u) {
    float f; memcpy(&f, &u, 4); return f;
}

__global__ void prep_kernel(const float* __restrict__ W_rec,
                            int* __restrict__ meta, char* __restrict__ wsB) {
    __shared__ int cnt[NN], sorted[NN];
    __shared__ int pkp[72], pOff[72];
    __shared__ int wBase[8];
    const int t = threadIdx.x;

    // zero stream region (pads + prefetch tail)
    for (int i = t; i < 28672 / 4; i += 256) ((int*)(wsB + STREAM_BASE))[i] = 0;

    if (t < NN) {
        int c = 0;
        for (int j = 0; j < NN; ++j) c += (W_rec[t * NN + j] != 0.0f);
        cnt[t] = c;
    }
    __syncthreads();
    if (t < NN) {   // deterministic descending rank (ties by index)
        int ct = cnt[t], r = 0;
        for (int j = 0; j < NN; ++j) {
            int cj = cnt[j];
            r += (cj > ct) || (cj == ct && j < t);
        }
        sorted[r] = t;
    }
    __syncthreads();
    if (t == 0) {
        int wsum[8][SLOTS];   // pair index per wave/slot
        for (int i = 0; i < 72; ++i) {
            int c0 = cnt[sorted[2 * i]], c1 = cnt[sorted[2 * i + 1]];
            int mx = c0 > c1 ? c0 : c1; if (mx < 1) mx = 1;
            pkp[i] = (mx + 3) & ~3;
            int r = i / 8, pos = i % 8;
            int w = (r & 1) ? (7 - pos) : pos;     // snake deal
            wsum[w][r] = i;
        }
        int off = 0;
        for (int w = 0; w < 8; ++w) {
            wBase[w] = off;
            for (int r = 0; r < SLOTS; ++r) {
                int p = wsum[w][r];
                pOff[p] = off;
                off += pkp[p] * 16;                // kp entries x 2 halves x 8B
            }
            for (int r = 0; r < SLOTS; ++r) {      // meta in slot order
                int p = wsum[w][r];
                meta[w * META_STRIDE + 1 + r * 3]     = pkp[p];
                meta[w * META_STRIDE + 1 + r * 3 + 1] = sorted[2 * p];
                meta[w * META_STRIDE + 1 + r * 3 + 2] = sorted[2 * p + 1];
            }
            meta[w * META_STRIDE] = wBase[w];
        }
    }
    __syncthreads();
    if (t < 144) {          // fill streams: pair i = t>>1, half h = t&1
        int i = t >> 1, h = t & 1;
        int row = sorted[2 * i + h];
        char* base = wsB + STREAM_BASE + pOff[i] + h * 32;
        int k = 0;
        for (int j = 0; j < NN; ++j) {
            float w = W_rec[row * NN + j];
            if (w != 0.0f) {
                int c = k >> 2, pos = k & 3;
                char* a = base + c * 64 + (pos >= 2 ? 16 : 0) + (pos & 1) * 8;
                *(unsigned*)a     = (unsigned)j * 128u;   // col * NB * 4
                *(float*)(a + 4)  = w;
                ++k;
            }
        }
    }
}

// 4 entries from two uint4 regs: {colByte,w} pairs; k-ascending f64 FMA.
#define GF4(S0, S1)                                                     \
    {                                                                   \
        float a0 = *(const float*)(ldsB + ((S0).x + lro));              \
        float a1 = *(const float*)(ldsB + ((S0).z + lro));              \
        float a2 = *(const float*)(ldsB + ((S1).x + lro));              \
        float a3 = *(const float*)(ldsB + ((S1).z + lro));              \
        rec += (double)u2f((S0).y) * (double)a0;                        \
        rec += (double)u2f((S0).w) * (double)a1;                        \
        rec += (double)u2f((S1).y) * (double)a2;                        \
        rec += (double)u2f((S1).w) * (double)a3;                        \
    }

__global__ __launch_bounds__(THREADS) void snn_kernel(
        const int*   __restrict__ actions,
        const float* __restrict__ spk,      // [B,8,115]
        const float* __restrict__ W_inh,    // [144,115]
        const int*   __restrict__ meta,
        const char*  __restrict__ wsB,
        const int*   __restrict__ nt_ptr,
        float*       __restrict__ out,      // [B,115]
        int B) {
    __shared__ float accF[2][NN * NB];      // 36864 B double-buffer
    __shared__ int   metaL[8 * META_STRIDE];

    const char* ldsB = (const char*)&accF[0][0];
    float*      nbF  = &accF[1][0];         // [NE][32] alias, pre-loop only

    const int t    = threadIdx.x;
    const int lane = t & 63;
    const int wid  = t >> 6;                // 0..7
    const int h    = lane >> 5;             // row-half within wave
    const int bb   = lane & 31;             // batch within block
    const int b0   = blockIdx.x * NB;
    const int b    = b0 + bb;
    const int ticks = *nt_ptr;

    int vz;
    asm volatile("v_mov_b32 %0, 0" : "=v"(vz));

    if (t < 8 * META_STRIDE) metaL[t] = meta[t];

    // stage neighbor sums nbF[e*32+bb]
    for (int p = t; p < NB * NE; p += THREADS) {
        int bb2 = p / NE;
        int e   = p - bb2 * NE;
        float s = 0.0f;
        if (b0 + bb2 < B) {
            const float* sp = spk + ((size_t)(b0 + bb2) * 8) * NE + e;
            #pragma unroll
            for (int n = 0; n < 8; ++n) s += sp[n * NE];
        }
        nbF[e * NB + bb2] = s;
    }
    for (int i = t; i < NN * NB; i += THREADS) accF[0][i] = 0.0f;
    __syncthreads();

    // wave metadata: kp wave-uniform (SGPR), rows per-lane (half-dependent)
    const int mBase = wid * META_STRIDE;
    const int sbase = __builtin_amdgcn_readfirstlane(metaL[mBase]);
    int skp[SLOTS], rows[SLOTS];
    #pragma unroll
    for (int r = 0; r < SLOTS; ++r) {
        skp[r]  = __builtin_amdgcn_readfirstlane(metaL[mBase + 1 + r * 3]);
        rows[r] = metaL[mBase + 1 + r * 3 + 1 + h];
    }

    // drives (fp64, e ascending — same association as R4-R13)
    double drv[SLOTS];
    {
        int a = (b < B) ? actions[b] : 4;
        int cs = ((a == 0) ? 5 : (a == 1) ? 1 : (a == 2) ? 3 : (a == 3) ? 7 : 4) * 16;
        #pragma unroll
        for (int r = 0; r < SLOTS; ++r) {
            double inh = 0.0;
            for (int e = 0; e < NE; ++e)
                inh += (double)nbF[e * NB + bb] * (double)W_inh[rows[r] * NE + e];
            double ic = (rows[r] >= cs && rows[r] < cs + 16) ? 5.0 : 0.0;
            drv[r] = 0.5 * ic - 0.5 * inh;
        }
    }

    // per-lane flat stream pointer: wave base + half offset (chunk-interleaved)
    const uint4* pBase = (const uint4*)(wsB + STREAM_BASE + sbase) + (h << 1) + vz;

    double v[SLOTS];
    float  accv[SLOTS];
    #pragma unroll
    for (int r = 0; r < SLOTS; ++r) { v[r] = 0.0; accv[r] = 0.0f; }

    for (int tk = 0; tk < ticks; ++tk) {
        __syncthreads();   // prev tick's acc writes (or initial zeros) visible
        const unsigned rbOff = (tk & 1) ? 18432u : 0u;
        const unsigned lro   = (unsigned)(bb * 4) + rbOff;
        char* WbB = (char*)ldsB + ((tk & 1) ? 0u : 18432u);

        // prime: my chunk0 = q[0],q[1]; my chunk1 = q[4],q[5]
        const uint4* q = pBase;
        uint4 SA0 = q[0], SA1 = q[1];
        uint4 SB0 = q[4], SB1 = q[5];

        #pragma unroll
        for (int r = 0; r < SLOTS; ++r) {
            double rec = 0.0;
            int k = 0;
            const int kend = skp[r];
            while (k + 8 <= kend) {          // 8 entries/iter, zero-mov steady
                GF4(SA0, SA1);
                SA0 = q[8];  SA1 = q[9];
                GF4(SB0, SB1);
                SB0 = q[12]; SB1 = q[13];
                q += 8; k += 8;
            }
            if (k < kend) {                  // kp%8==4 leftover chunk
                GF4(SA0, SA1);
                SA0 = SB0; SA1 = SB1;
                SB0 = q[8]; SB1 = q[9];
                q += 4;
            }
            // invariant: SA = next pair's chunk0, SB = chunk1 (flat stream)
            const int o = rows[r];
            double x = drv[r] + 0.3 * ((o < NE) ? rec : -rec);
            double vv = v[r];
            vv += (x - vv) * 0.5;
            double sd = (vv >= 1.0) ? 1.0 : 0.0;
            vv *= (1.0 - sd);
            v[r] = vv;
            accv[r] += (float)sd;
            *(float*)(WbB + (unsigned)o * 128u + bb * 4) = accv[r];
        }
    }

    if (b < B) {
        #pragma unroll
        for (int r = 0; r < SLOTS; ++r) {
            int o = rows[r];
            if (o < NE) out[(size_t)b * NE + o] = accv[r];
        }
    }
}

extern "C" void kernel_launch(void* const* d_in, const int* in_sizes, int n_in,
                              void* d_out, int out_size, void* d_ws, size_t ws_size,
                              hipStream_t stream) {
    const int*   actions = (const int*)  d_in[0];
    const float* spk     = (const float*)d_in[1];
    const float* W_rec   = (const float*)d_in[2];
    const float* W_inh   = (const float*)d_in[3];
    const int*   nt      = (const int*)  d_in[4];
    float* out = (float*)d_out;
    int B = in_sizes[0];

    int*  meta = (int*)d_ws;
    char* wsB  = (char*)d_ws;

    prep_kernel<<<1, 256, 0, stream>>>(W_rec, meta, wsB);
    int nblocks = (B + NB - 1) / NB;
    snn_kernel<<<nblocks, THREADS, 0, stream>>>(actions, spk, W_inh, meta, wsB,
                                                nt, out, B);
}

// Round 15
// 353.875 us; speedup vs baseline: 1.1398x; 1.1398x over previous
//
#include <hip/hip_runtime.h>
#include <string.h>

// TopographicIntentMap R15: R7 skeleton (362us, best) + nnz-balanced wave deal.
// R7's convoy: one barrier/tick -> tick wall = slowest wave; row nnz is
// binomial (14.4 +/- 3.6), 9-row wave sums vary ~10-15% after x4 padding.
// Prep rank-sorts rows by nnz (deterministic), snake-deals to 16 waves x 9
// slots (serpentine by slot -> wave sums equal within ~1-2%), stream laid
// wave-major/slot-contiguous so each wave runs R7's byte-identical flat
// mov-free depth-2 loop. NOTHING else changes: b32 gathers, vz vector-path
// stream ptr, f32 acc dbuf (73.7KB), one barrier/tick, one tick body.
// Numerics: identical exact-f64 pipeline (absmax 0 in R3-R14); the deal only
// moves WHERE each row's k-ascending sum is computed.

#define NN 144
#define NE 115
#define NB 64            // batches per block (= lanes)
#define SLOTS 9          // rows per wave: 16*9 = 144
#define THREADS 1024

#define STREAM_BASE 4096 // stream region in ws (bytes); meta at ws[0..2KB)
#define META_STRIDE 32   // ints per wave: [0]=base entry idx, [1+r]=row, [10+r]=kp

__device__ __forceinline__ float u2f(unsigned u) {
    float f; memcpy(&f, &u, 4); return f;
}

__global__ void prep_kernel(const float* __restrict__ W_rec,
                            int* __restrict__ meta, char* __restrict__ wsB) {
    __shared__ int cnt[NN], sorted[NN], rowOff[NN];
    const int t = threadIdx.x;

    // zero stream region (pads + prefetch-overrun tail): 48KB
    for (int i = t; i < 49152 / 4; i += 256) ((int*)(wsB + STREAM_BASE))[i] = 0;

    if (t < NN) {
        int c = 0;
        for (int j = 0; j < NN; ++j) c += (W_rec[t * NN + j] != 0.0f);
        cnt[t] = c;
    }
    __syncthreads();
    if (t < NN) {   // deterministic descending rank (ties by index)
        int ct = cnt[t], r = 0;
        for (int j = 0; j < NN; ++j) {
            int cj = cnt[j];
            r += (cj > ct) || (cj == ct && j < t);
        }
        sorted[r] = t;
    }
    __syncthreads();
    if (t == 0) {
        int off = 0;
        for (int w = 0; w < 16; ++w) {
            int* m = meta + w * META_STRIDE;
            m[0] = off;                          // wave base entry index
            for (int r = 0; r < SLOTS; ++r) {
                int pos = (r & 1) ? (15 - w) : w;        // snake deal
                int row = sorted[r * 16 + pos];
                int c = cnt[row];
                int kp = ((c < 1 ? 1 : c) + 3) & ~3;     // pad to x4, min 4
                m[1 + r]  = row;
                m[10 + r] = kp;
                rowOff[row] = off;
                off += kp;
            }
        }
    }
    __syncthreads();
    if (t < NN) {            // fill each row's entries at its offset
        char* base = wsB + STREAM_BASE + (size_t)rowOff[t] * 8;
        int k = 0;
        for (int j = 0; j < NN; ++j) {
            float w = W_rec[t * NN + j];
            if (w != 0.0f) {
                *(unsigned*)(base + (size_t)k * 8)     = (unsigned)j * 256u;
                *(float*)(base + (size_t)k * 8 + 4)    = w;
                ++k;
            }
        }
        // (pads already zeroed; zero pads are exact +0.0*acc[0] no-ops)
    }
}

// 4 entries from two uint4 regs: {colByte,w} pairs; k-ascending f64 FMA.
#define GFMA4(S0, S1)                                                   \
    {                                                                   \
        float a0 = *(const float*)(ldsB + ((S0).x + lro));              \
        float a1 = *(const float*)(ldsB + ((S0).z + lro));              \
        float a2 = *(const float*)(ldsB + ((S1).x + lro));              \
        float a3 = *(const float*)(ldsB + ((S1).z + lro));              \
        rec += (double)u2f((S0).y) * (double)a0;                        \
        rec += (double)u2f((S0).w) * (double)a1;                        \
        rec += (double)u2f((S1).y) * (double)a2;                        \
        rec += (double)u2f((S1).w) * (double)a3;                        \
    }

__global__ __launch_bounds__(THREADS) void snn_kernel(
        const int*   __restrict__ actions,
        const float* __restrict__ spk,      // [B,8,115]
        const float* __restrict__ W_inh,    // [144,115]
        const int*   __restrict__ meta,
        const uint4* __restrict__ csrQ,     // stream: 2 entries per uint4
        const int*   __restrict__ nt_ptr,
        float*       __restrict__ out,      // [B,115]
        int B) {
    __shared__ float accF[2][NN * NB];      // 73728 B, double-buffered
    __shared__ int   metaL[16 * META_STRIDE];

    const char* ldsB = (const char*)&accF[0][0];
    float* nbF = &accF[1][0];               // [NE][65] alias, pre-loop only

    const int t    = threadIdx.x;
    const int lane = t & 63;
    const int wid  = t >> 6;
    const int b0   = blockIdx.x * NB;
    const int b    = b0 + lane;
    const int ticks = *nt_ptr;

    // opaque per-lane zero: keeps the CSR stream on the vector VMEM path
    int vz;
    asm volatile("v_mov_b32 %0, 0" : "=v"(vz));

    if (t < 16 * META_STRIDE) metaL[t] = meta[t];

    // stage neighbor sums into nbF[e][bb]
    for (int p = t; p < NB * NE; p += THREADS) {
        int bb = p / NE;
        int e  = p - bb * NE;
        float s = 0.0f;
        if (b0 + bb < B) {
            const float* sp = spk + ((size_t)(b0 + bb) * 8) * NE + e;
            #pragma unroll
            for (int n = 0; n < 8; ++n) s += sp[n * NE];
        }
        nbF[e * (NB + 1) + bb] = s;
    }
    for (int i = t; i < NN * NB; i += THREADS) accF[0][i] = 0.0f;
    __syncthreads();

    // wave-uniform metadata (SGPRs)
    const int mb = wid * META_STRIDE;
    const int sbase = __builtin_amdgcn_readfirstlane(metaL[mb]);
    int rows[SLOTS], skp[SLOTS];
    #pragma unroll
    for (int r = 0; r < SLOTS; ++r) {
        rows[r] = __builtin_amdgcn_readfirstlane(metaL[mb + 1 + r]);
        skp[r]  = __builtin_amdgcn_readfirstlane(metaL[mb + 10 + r]);
    }

    // per-row drives (fp64, e ascending — same association as R4-R14)
    double drv[SLOTS];
    {
        int a = (b < B) ? actions[b] : 4;
        int cs = ((a == 0) ? 5 : (a == 1) ? 1 : (a == 2) ? 3 : (a == 3) ? 7 : 4) * 16;
        #pragma unroll
        for (int r = 0; r < SLOTS; ++r) {
            double inh = 0.0;
            for (int e = 0; e < NE; ++e)
                inh += (double)nbF[e * (NB + 1) + lane]
                     * (double)W_inh[rows[r] * NE + e];
            double ic = (rows[r] >= cs && rows[r] < cs + 16) ? 5.0 : 0.0;
            drv[r] = 0.5 * ic - 0.5 * inh;
        }
    }

    const uint4* pBase = csrQ + (sbase >> 1) + vz;   // per-lane ptr (VMEM)

    double v[SLOTS];
    float  accv[SLOTS];
    #pragma unroll
    for (int r = 0; r < SLOTS; ++r) { v[r] = 0.0; accv[r] = 0.0f; }

    for (int tk = 0; tk < ticks; ++tk) {
        __syncthreads();   // prev tick's acc writes (or initial zeros) visible
        const unsigned rbOff = (tk & 1) ? 36864u : 0u;
        const unsigned lro   = (unsigned)(lane * 4) + rbOff;
        char* WbB = (char*)ldsB + ((tk & 1) ? 0u : 36864u);

        // prime: SA = entries 0..3, SB = 4..7 of this wave's flat stream
        const uint4* p = pBase;
        uint4 SA0 = p[0], SA1 = p[1];
        uint4 SB0 = p[2], SB1 = p[3];

        #pragma unroll
        for (int r = 0; r < SLOTS; ++r) {
            double rec = 0.0;
            int k = 0;
            const int kend = skp[r];
            // steady state: 2 chunks (8 entries)/iter, zero rotation movs
            while (k + 8 <= kend) {
                GFMA4(SA0, SA1);
                SA0 = p[4]; SA1 = p[5];
                GFMA4(SB0, SB1);
                SB0 = p[6]; SB1 = p[7];
                p += 4; k += 8;
            }
            if (k < kend) {                  // kend%8==4 leftover chunk
                GFMA4(SA0, SA1);
                SA0 = SB0; SA1 = SB1;
                SB0 = p[4]; SB1 = p[5];
                p += 2;
            }
            // invariant: SA = next slot's first chunk, SB = second
            const int o = rows[r];
            double x = drv[r] + 0.3 * ((o < NE) ? rec : -rec);
            double vv = v[r];
            vv += (x - vv) * 0.5;
            double sd = (vv >= 1.0) ? 1.0 : 0.0;
            vv *= (1.0 - sd);
            v[r] = vv;
            accv[r] += (float)sd;
            *(float*)(WbB + ((unsigned)o << 8) + lane * 4) = accv[r];
        }
    }

    if (b < B) {
        #pragma unroll
        for (int r = 0; r < SLOTS; ++r) {
            int o = rows[r];
            if (o < NE) out[(size_t)b * NE + o] = accv[r];
        }
    }
}

extern "C" void kernel_launch(void* const* d_in, const int* in_sizes, int n_in,
                              void* d_out, int out_size, void* d_ws, size_t ws_size,
                              hipStream_t stream) {
    const int*   actions = (const int*)  d_in[0];
    const float* spk     = (const float*)d_in[1];
    const float* W_rec   = (const float*)d_in[2];
    const float* W_inh   = (const float*)d_in[3];
    const int*   nt      = (const int*)  d_in[4];
    float* out = (float*)d_out;
    int B = in_sizes[0];

    int*  meta = (int*)d_ws;
    char* wsB  = (char*)d_ws;
    const uint4* csrQ = (const uint4*)(wsB + STREAM_BASE);

    prep_kernel<<<1, 256, 0, stream>>>(W_rec, meta, wsB);
    int nblocks = (B + NB - 1) / NB;
    snn_kernel<<<nblocks, THREADS, 0, stream>>>(actions, spk, W_inh, meta, csrQ,
                                                nt, out, B);
}